// Round 1
// baseline (17164.853 us; speedup 1.0000x reference)
//
#include <hip/hip_runtime.h>
#include <hip/hip_bf16.h>

#define D_MODEL 1024
#define N_HEADS 16
#define DH 64
#define CHUNK_LEN 50
#define MEM_LEN 16
#define TT 66            // MEM_LEN + CHUNK_LEN
#define BB 64
#define LL 2000
#define NCHUNK 40
#define MTOK (BB*TT)     // 4224

typedef __attribute__((ext_vector_type(8))) short short8;
typedef __attribute__((ext_vector_type(4))) float f32x4;

typedef __attribute__((address_space(1))) const void GVoid;
typedef __attribute__((address_space(3))) void LVoid;

__device__ __forceinline__ void gload16(const void* g, void* l) {
  __builtin_amdgcn_global_load_lds((GVoid*)g, (LVoid*)l, 16, 0, 0);
}

__device__ __forceinline__ float bf2f(__hip_bfloat16 h){ return __bfloat162float(h); }

// ---------------- weight fp32 -> bf16 ----------------
__global__ __launch_bounds__(256) void f2b_kernel(const float* __restrict__ in,
                                                  __hip_bfloat16* __restrict__ out, int n) {
  int i = (blockIdx.x * 256 + threadIdx.x) * 4;
  if (i < n) {
    float4 v = *(const float4*)(in + i);
    out[i+0] = __float2bfloat16(v.x);
    out[i+1] = __float2bfloat16(v.y);
    out[i+2] = __float2bfloat16(v.z);
    out[i+3] = __float2bfloat16(v.w);
  }
}

// ---------------- build z (gather + mem + pos) fused with LN1 ----------------
__global__ __launch_bounds__(256) void build_z_ln(
    const int* __restrict__ in_prob, const int* __restrict__ in_skill,
    const float* __restrict__ emb_p, const float* __restrict__ emb_s,
    const float* __restrict__ mem_src, int mem_bstride,
    const float* __restrict__ pos,
    const float* __restrict__ gam, const float* __restrict__ bet,
    float* __restrict__ z, __hip_bfloat16* __restrict__ zn, int chunk)
{
  int row = blockIdx.x;                 // 0..MTOK-1
  int b = row / TT, t = row % TT;
  int tid = threadIdx.x;
  int d = tid * 4;
  float4 v;
  if (t < MEM_LEN) {
    v = *(const float4*)(mem_src + (size_t)b*mem_bstride + t*D_MODEL + d);
  } else {
    int tok = chunk*CHUNK_LEN + (t - MEM_LEN);
    int p = in_prob[b*LL + tok];
    int s = in_skill[b*LL + tok];
    float4 vp = *(const float4*)(emb_p + (size_t)p*D_MODEL + d);
    float4 vs = *(const float4*)(emb_s + (size_t)s*D_MODEL + d);
    v = make_float4(vp.x+vs.x, vp.y+vs.y, vp.z+vs.z, vp.w+vs.w);
  }
  float4 pv = *(const float4*)(pos + t*D_MODEL + d);
  v.x += pv.x; v.y += pv.y; v.z += pv.z; v.w += pv.w;
  *(float4*)(z + (size_t)row*D_MODEL + d) = v;
  // LN over the row
  float sum = v.x+v.y+v.z+v.w;
  float sq  = v.x*v.x+v.y*v.y+v.z*v.z+v.w*v.w;
  #pragma unroll
  for (int off = 32; off; off >>= 1) {
    sum += __shfl_down(sum, off, 64);
    sq  += __shfl_down(sq,  off, 64);
  }
  __shared__ float rs_[4], rq_[4];
  int wave = tid >> 6, lane = tid & 63;
  if (lane == 0) { rs_[wave] = sum; rq_[wave] = sq; }
  __syncthreads();
  sum = rs_[0]+rs_[1]+rs_[2]+rs_[3];
  sq  = rq_[0]+rq_[1]+rq_[2]+rq_[3];
  float mu  = sum * (1.0f/D_MODEL);
  float var = sq  * (1.0f/D_MODEL) - mu*mu;
  float rstd = rsqrtf(var + 1e-5f);
  float4 gv = *(const float4*)(gam + d);
  float4 bv = *(const float4*)(bet + d);
  __hip_bfloat16* o = zn + (size_t)row*D_MODEL + d;
  o[0] = __float2bfloat16((v.x-mu)*rstd*gv.x + bv.x);
  o[1] = __float2bfloat16((v.y-mu)*rstd*gv.y + bv.y);
  o[2] = __float2bfloat16((v.z-mu)*rstd*gv.z + bv.z);
  o[3] = __float2bfloat16((v.w-mu)*rstd*gv.w + bv.w);
}

// ---------------- plain LN (z fp32 -> bf16 out) ----------------
__global__ __launch_bounds__(256) void ln_kernel(
    const float* __restrict__ z, const float* __restrict__ gam, const float* __restrict__ bet,
    __hip_bfloat16* __restrict__ out)
{
  int row = blockIdx.x;
  int tid = threadIdx.x;
  int d = tid * 4;
  float4 v = *(const float4*)(z + (size_t)row*D_MODEL + d);
  float sum = v.x+v.y+v.z+v.w;
  float sq  = v.x*v.x+v.y*v.y+v.z*v.z+v.w*v.w;
  #pragma unroll
  for (int off = 32; off; off >>= 1) {
    sum += __shfl_down(sum, off, 64);
    sq  += __shfl_down(sq,  off, 64);
  }
  __shared__ float rs_[4], rq_[4];
  int wave = tid >> 6, lane = tid & 63;
  if (lane == 0) { rs_[wave] = sum; rq_[wave] = sq; }
  __syncthreads();
  sum = rs_[0]+rs_[1]+rs_[2]+rs_[3];
  sq  = rq_[0]+rq_[1]+rq_[2]+rq_[3];
  float mu  = sum * (1.0f/D_MODEL);
  float var = sq  * (1.0f/D_MODEL) - mu*mu;
  float rstd = rsqrtf(var + 1e-5f);
  float4 gv = *(const float4*)(gam + d);
  float4 bv = *(const float4*)(bet + d);
  __hip_bfloat16* o = out + (size_t)row*D_MODEL + d;
  o[0] = __float2bfloat16((v.x-mu)*rstd*gv.x + bv.x);
  o[1] = __float2bfloat16((v.y-mu)*rstd*gv.y + bv.y);
  o[2] = __float2bfloat16((v.z-mu)*rstd*gv.z + bv.z);
  o[3] = __float2bfloat16((v.w-mu)*rstd*gv.w + bv.w);
}

// ---------------- attention (per b,h block) ----------------
__global__ __launch_bounds__(256) void attn_kernel(
    const __hip_bfloat16* __restrict__ qkv, __hip_bfloat16* __restrict__ attn_o)
{
  __shared__ float qs[TT*DH], ks[TT*DH], vs[TT*DH];
  __shared__ float sc[TT*67];
  int bh = blockIdx.x; int b = bh >> 4, h = bh & 15;
  int tid = threadIdx.x;
  const __hip_bfloat16* base = qkv + (size_t)b*TT*3072 + h*DH;
  for (int i = tid; i < TT*DH; i += 256) {
    int t = i >> 6, d2 = i & 63;
    const __hip_bfloat16* rp = base + (size_t)t*3072 + d2;
    qs[i] = bf2f(rp[0]);
    ks[i] = bf2f(rp[1024]);
    vs[i] = bf2f(rp[2048]);
  }
  __syncthreads();
  for (int p = tid; p < TT*TT; p += 256) {
    int qi = p / TT, kj = p % TT;
    float s;
    if (qi >= MEM_LEN && kj >= MEM_LEN && kj > qi) {
      s = -1e9f;
    } else {
      float acc = 0.f;
      const float* qr = qs + qi*DH;
      const float* kr = ks + kj*DH;
      #pragma unroll 8
      for (int d2 = 0; d2 < DH; d2++) acc += qr[d2]*kr[d2];
      s = acc * 0.125f;   // 1/sqrt(64)
    }
    sc[qi*67 + kj] = s;
  }
  __syncthreads();
  if (tid < TT) {
    float* r = sc + tid*67;
    float m = -1e30f;
    for (int j = 0; j < TT; j++) m = fmaxf(m, r[j]);
    float ssum = 0.f;
    for (int j = 0; j < TT; j++) { float e = __expf(r[j]-m); r[j] = e; ssum += e; }
    float inv = 1.f/ssum;
    for (int j = 0; j < TT; j++) r[j] *= inv;
  }
  __syncthreads();
  for (int p = tid; p < TT*DH; p += 256) {
    int qi = p >> 6, d2 = p & 63;
    float acc = 0.f;
    const float* ar = sc + qi*67;
    for (int kj = 0; kj < TT; kj++) acc += ar[kj]*vs[kj*DH + d2];
    attn_o[((size_t)b*TT + qi)*D_MODEL + h*DH + d2] = __float2bfloat16(acc);
  }
}

// ---------------- finalize: enc_out rows, mem candidate ----------------
__global__ __launch_bounds__(256) void finalize_kernel(
    const float* __restrict__ z, float* __restrict__ enc_out,
    float* __restrict__ mem, __hip_bfloat16* __restrict__ memcand, int chunk)
{
  int row = blockIdx.x; int b = row / TT, t = row % TT;
  int d = threadIdx.x * 4;
  float4 v = *(const float4*)(z + (size_t)row*D_MODEL + d);
  if (t >= MEM_LEN) {
    size_t o = ((size_t)b*LL + chunk*CHUNK_LEN + (t - MEM_LEN))*D_MODEL + d;
    *(float4*)(enc_out + o) = v;
  } else {
    size_t mrow = (size_t)b*MEM_LEN + t;
    if (chunk == 0) {
      *(float4*)(mem + mrow*D_MODEL + d) = v;
    } else {
      __hip_bfloat16* o = memcand + mrow*D_MODEL + d;
      o[0] = __float2bfloat16(v.x);
      o[1] = __float2bfloat16(v.y);
      o[2] = __float2bfloat16(v.z);
      o[3] = __float2bfloat16(v.w);
    }
  }
}

// ---------------- copy mem -> output tail ----------------
__global__ __launch_bounds__(256) void copy_mem_kernel(const float* __restrict__ mem,
                                                       float* __restrict__ out) {
  int i = (blockIdx.x * 256 + threadIdx.x) * 4;
  float4 v = *(const float4*)(mem + i);
  *(float4*)(out + i) = v;
}

// ---------------- GEMM: C = A(MxK) @ Bw(NxK)^T, bf16 in / f32 acc ----------------
#define EPI_QKV  0
#define EPI_RESID 1
#define EPI_RELU 2
#define EPI_GATE 3

template<int EPI>
__global__ __launch_bounds__(256) void gemm_bt(
    const __hip_bfloat16* __restrict__ A,
    const __hip_bfloat16* __restrict__ Bw,
    const float* __restrict__ bias,
    float* __restrict__ zres,
    __hip_bfloat16* __restrict__ obf,
    float* __restrict__ mem,
    int K, int ldo)
{
  __shared__ short As[128*32];
  __shared__ short Bs[128*32];
  int tid = threadIdx.x;
  int lane = tid & 63, wave = tid >> 6;
  int wr = wave >> 1, wc = wave & 1;
  int tm = blockIdx.y * 128, tn = blockIdx.x * 128;
  f32x4 acc[4][4] = {};
  const short* Ash = (const short*)A;
  const short* Bsh = (const short*)Bw;
  int e0 = tid * 8;
  int r0 = e0 >> 5, c0 = e0 & 31;

  for (int kt = 0; kt < K; kt += 32) {
    gload16(Ash + (size_t)(tm +      r0)*K + kt + c0, (char*)As +        wave*1024);
    gload16(Ash + (size_t)(tm + 64 + r0)*K + kt + c0, (char*)As + 4096 + wave*1024);
    gload16(Bsh + (size_t)(tn +      r0)*K + kt + c0, (char*)Bs +        wave*1024);
    gload16(Bsh + (size_t)(tn + 64 + r0)*K + kt + c0, (char*)Bs + 4096 + wave*1024);
    __syncthreads();
    short8 af[4], bfr[4];
    int ko = (lane >> 4) * 8;
    int rr = lane & 15;
    #pragma unroll
    for (int m = 0; m < 4; m++)
      af[m] = *(const short8*)(As + (wr*64 + m*16 + rr)*32 + ko);
    #pragma unroll
    for (int n = 0; n < 4; n++)
      bfr[n] = *(const short8*)(Bs + (wc*64 + n*16 + rr)*32 + ko);
    #pragma unroll
    for (int m = 0; m < 4; m++)
      #pragma unroll
      for (int n = 0; n < 4; n++)
        acc[m][n] = __builtin_amdgcn_mfma_f32_16x16x32_bf16(af[m], bfr[n], acc[m][n], 0, 0, 0);
    __syncthreads();
  }

  int rbase = tm + wr*64 + ((lane >> 4) << 2);
  int cbase = tn + wc*64 + (lane & 15);
  #pragma unroll
  for (int n = 0; n < 4; n++) {
    int col = cbase + n*16;
    float bs = bias[col];
    #pragma unroll
    for (int m = 0; m < 4; m++) {
      #pragma unroll
      for (int i = 0; i < 4; i++) {
        int r = rbase + m*16 + i;
        float v = acc[m][n][i] + bs;
        if constexpr (EPI == EPI_QKV) {
          obf[(size_t)r*ldo + col] = __float2bfloat16(v);
        } else if constexpr (EPI == EPI_RESID) {
          zres[(size_t)r*D_MODEL + col] += v;
        } else if constexpr (EPI == EPI_RELU) {
          obf[(size_t)r*ldo + col] = __float2bfloat16(fmaxf(v, 0.f));
        } else { // EPI_GATE: r = b*16+t over mem rows
          float g = 1.f / (1.f + __expf(-v));
          int b = r >> 4, t = r & 15;
          float mc = zres[((size_t)b*TT + t)*D_MODEL + col];
          size_t mi = (size_t)r*D_MODEL + col;
          float mo = mem[mi];
          mem[mi] = g*mc + (1.f - g)*mo;
        }
      }
    }
  }
}

extern "C" void kernel_launch(void* const* d_in, const int* in_sizes, int n_in,
                              void* d_out, int out_size, void* d_ws, size_t ws_size,
                              hipStream_t stream) {
  const int*   in_prob  = (const int*)d_in[0];
  const int*   in_skill = (const int*)d_in[1];
  const float* emb_p    = (const float*)d_in[2];
  const float* emb_s    = (const float*)d_in[3];
  const float* mem_init = (const float*)d_in[4];
  const float* pos      = (const float*)d_in[5];
  const float* w_qkv    = (const float*)d_in[6];
  const float* b_qkv    = (const float*)d_in[7];
  const float* w_out    = (const float*)d_in[8];
  const float* b_out    = (const float*)d_in[9];
  const float* w1       = (const float*)d_in[10];
  const float* b1       = (const float*)d_in[11];
  const float* w2       = (const float*)d_in[12];
  const float* b2       = (const float*)d_in[13];
  const float* g_attn   = (const float*)d_in[14];
  const float* be_attn  = (const float*)d_in[15];
  const float* g_ffn    = (const float*)d_in[16];
  const float* be_ffn   = (const float*)d_in[17];
  const float* w_gate   = (const float*)d_in[18];
  const float* b_gate   = (const float*)d_in[19];

  float* enc_out = (float*)d_out;
  float* mem_out = enc_out + (size_t)BB*LL*D_MODEL;

  char* ws = (char*)d_ws;
  size_t off = 0;
  auto alloc = [&](size_t bytes) -> char* {
    char* p = ws + off;
    off += (bytes + 255) & ~(size_t)255;
    return p;
  };
  __hip_bfloat16* wqkv_bf = (__hip_bfloat16*)alloc((size_t)3072*1024*2);
  __hip_bfloat16* wout_bf = (__hip_bfloat16*)alloc((size_t)1024*1024*2);
  __hip_bfloat16* w1_bf   = (__hip_bfloat16*)alloc((size_t)4096*1024*2);
  __hip_bfloat16* w2_bf   = (__hip_bfloat16*)alloc((size_t)1024*4096*2);
  __hip_bfloat16* wgate_bf= (__hip_bfloat16*)alloc((size_t)1024*1024*2);
  float*          z       = (float*)alloc((size_t)MTOK*D_MODEL*4);
  __hip_bfloat16* zn      = (__hip_bfloat16*)alloc((size_t)MTOK*D_MODEL*2);
  __hip_bfloat16* qkv     = (__hip_bfloat16*)alloc((size_t)MTOK*3072*2);
  __hip_bfloat16* ao      = (__hip_bfloat16*)alloc((size_t)MTOK*D_MODEL*2);
  __hip_bfloat16* hb      = (__hip_bfloat16*)alloc((size_t)MTOK*D_MODEL*2);
  __hip_bfloat16* fh      = (__hip_bfloat16*)alloc((size_t)MTOK*4096*2);
  __hip_bfloat16* mcb     = (__hip_bfloat16*)alloc((size_t)1024*1024*2);
  float*          mem     = (float*)alloc((size_t)1024*1024*4);
  if (off > ws_size) return;  // workspace too small -> fail loudly via wrong output

  // weights -> bf16 (cheap, once per call)
  f2b_kernel<<<(3072*1024)/1024, 256, 0, stream>>>(w_qkv, wqkv_bf, 3072*1024);
  f2b_kernel<<<(1024*1024)/1024, 256, 0, stream>>>(w_out, wout_bf, 1024*1024);
  f2b_kernel<<<(4096*1024)/1024, 256, 0, stream>>>(w1, w1_bf, 4096*1024);
  f2b_kernel<<<(1024*4096)/1024, 256, 0, stream>>>(w2, w2_bf, 1024*4096);
  f2b_kernel<<<(1024*1024)/1024, 256, 0, stream>>>(w_gate, wgate_bf, 1024*1024);

  for (int c = 0; c < NCHUNK; c++) {
    const float* msrc = (c == 0) ? mem_init : mem;
    int mbs = (c == 0) ? 0 : MEM_LEN*D_MODEL;
    build_z_ln<<<MTOK, 256, 0, stream>>>(in_prob, in_skill, emb_p, emb_s,
                                         msrc, mbs, pos, g_attn, be_attn, z, zn, c);
    gemm_bt<EPI_QKV><<<dim3(3072/128, MTOK/128), 256, 0, stream>>>(
        zn, wqkv_bf, b_qkv, nullptr, qkv, nullptr, 1024, 3072);
    attn_kernel<<<BB*N_HEADS, 256, 0, stream>>>(qkv, ao);
    gemm_bt<EPI_RESID><<<dim3(1024/128, MTOK/128), 256, 0, stream>>>(
        ao, wout_bf, b_out, z, nullptr, nullptr, 1024, 1024);
    ln_kernel<<<MTOK, 256, 0, stream>>>(z, g_ffn, be_ffn, hb);
    gemm_bt<EPI_RELU><<<dim3(4096/128, MTOK/128), 256, 0, stream>>>(
        hb, w1_bf, b1, nullptr, fh, nullptr, 1024, 4096);
    gemm_bt<EPI_RESID><<<dim3(1024/128, MTOK/128), 256, 0, stream>>>(
        fh, w2_bf, b2, z, nullptr, nullptr, 4096, 1024);
    finalize_kernel<<<MTOK, 256, 0, stream>>>(z, enc_out, mem, mcb, c);
    if (c > 0) {
      gemm_bt<EPI_GATE><<<dim3(1024/128, 1024/128), 256, 0, stream>>>(
          mcb, wgate_bf, b_gate, z, nullptr, mem, 1024, 0);
    }
  }
  copy_mem_kernel<<<(1024*1024)/1024, 256, 0, stream>>>(mem, mem_out);
}

// Round 3
// 12953.275 us; speedup vs baseline: 1.3251x; 1.3251x over previous
//
#include <hip/hip_runtime.h>
#include <hip/hip_bf16.h>

#define D_MODEL 1024
#define N_HEADS 16
#define DH 64
#define CHUNK_LEN 50
#define MEM_LEN 16
#define TT 66            // MEM_LEN + CHUNK_LEN
#define BB 64
#define LL 2000
#define NCHUNK 40
#define MTOK (BB*TT)     // 4224

typedef _Float16 half8_t __attribute__((ext_vector_type(8)));
typedef __attribute__((ext_vector_type(4))) float f32x4;

typedef __attribute__((address_space(1))) const void GVoid;
typedef __attribute__((address_space(3))) void LVoid;

__device__ __forceinline__ void gload16(const void* g, void* l) {
  __builtin_amdgcn_global_load_lds((GVoid*)g, (LVoid*)l, 16, 0, 0);
}

// ---------------- weight fp32 -> fp16 ----------------
__global__ __launch_bounds__(256) void f2h_kernel(const float* __restrict__ in,
                                                  _Float16* __restrict__ out, int n) {
  int i = (blockIdx.x * 256 + threadIdx.x) * 4;
  if (i < n) {
    float4 v = *(const float4*)(in + i);
    out[i+0] = (_Float16)v.x;
    out[i+1] = (_Float16)v.y;
    out[i+2] = (_Float16)v.z;
    out[i+3] = (_Float16)v.w;
  }
}

// ---------------- build z (gather + mem + pos) fused with LN1 ----------------
__global__ __launch_bounds__(256) void build_z_ln(
    const int* __restrict__ in_prob, const int* __restrict__ in_skill,
    const float* __restrict__ emb_p, const float* __restrict__ emb_s,
    const float* __restrict__ mem_src, int mem_bstride,
    const float* __restrict__ pos,
    const float* __restrict__ gam, const float* __restrict__ bet,
    float* __restrict__ z, _Float16* __restrict__ zn, int chunk)
{
  int row = blockIdx.x;                 // 0..MTOK-1
  int b = row / TT, t = row % TT;
  int tid = threadIdx.x;
  int d = tid * 4;
  float4 v;
  if (t < MEM_LEN) {
    v = *(const float4*)(mem_src + (size_t)b*mem_bstride + t*D_MODEL + d);
  } else {
    int tok = chunk*CHUNK_LEN + (t - MEM_LEN);
    int p = in_prob[b*LL + tok];
    int s = in_skill[b*LL + tok];
    float4 vp = *(const float4*)(emb_p + (size_t)p*D_MODEL + d);
    float4 vs = *(const float4*)(emb_s + (size_t)s*D_MODEL + d);
    v = make_float4(vp.x+vs.x, vp.y+vs.y, vp.z+vs.z, vp.w+vs.w);
  }
  float4 pv = *(const float4*)(pos + t*D_MODEL + d);
  v.x += pv.x; v.y += pv.y; v.z += pv.z; v.w += pv.w;
  *(float4*)(z + (size_t)row*D_MODEL + d) = v;
  // LN over the row
  float sum = v.x+v.y+v.z+v.w;
  float sq  = v.x*v.x+v.y*v.y+v.z*v.z+v.w*v.w;
  #pragma unroll
  for (int off = 32; off; off >>= 1) {
    sum += __shfl_down(sum, off, 64);
    sq  += __shfl_down(sq,  off, 64);
  }
  __shared__ float rs_[4], rq_[4];
  int wave = tid >> 6, lane = tid & 63;
  if (lane == 0) { rs_[wave] = sum; rq_[wave] = sq; }
  __syncthreads();
  sum = rs_[0]+rs_[1]+rs_[2]+rs_[3];
  sq  = rq_[0]+rq_[1]+rq_[2]+rq_[3];
  float mu  = sum * (1.0f/D_MODEL);
  float var = sq  * (1.0f/D_MODEL) - mu*mu;
  float rstd = rsqrtf(var + 1e-5f);
  float4 gv = *(const float4*)(gam + d);
  float4 bv = *(const float4*)(bet + d);
  _Float16* o = zn + (size_t)row*D_MODEL + d;
  o[0] = (_Float16)((v.x-mu)*rstd*gv.x + bv.x);
  o[1] = (_Float16)((v.y-mu)*rstd*gv.y + bv.y);
  o[2] = (_Float16)((v.z-mu)*rstd*gv.z + bv.z);
  o[3] = (_Float16)((v.w-mu)*rstd*gv.w + bv.w);
}

// ---------------- plain LN (z fp32 -> fp16 out) ----------------
__global__ __launch_bounds__(256) void ln_kernel(
    const float* __restrict__ z, const float* __restrict__ gam, const float* __restrict__ bet,
    _Float16* __restrict__ out)
{
  int row = blockIdx.x;
  int tid = threadIdx.x;
  int d = tid * 4;
  float4 v = *(const float4*)(z + (size_t)row*D_MODEL + d);
  float sum = v.x+v.y+v.z+v.w;
  float sq  = v.x*v.x+v.y*v.y+v.z*v.z+v.w*v.w;
  #pragma unroll
  for (int off = 32; off; off >>= 1) {
    sum += __shfl_down(sum, off, 64);
    sq  += __shfl_down(sq,  off, 64);
  }
  __shared__ float rs_[4], rq_[4];
  int wave = tid >> 6, lane = tid & 63;
  if (lane == 0) { rs_[wave] = sum; rq_[wave] = sq; }
  __syncthreads();
  sum = rs_[0]+rs_[1]+rs_[2]+rs_[3];
  sq  = rq_[0]+rq_[1]+rq_[2]+rq_[3];
  float mu  = sum * (1.0f/D_MODEL);
  float var = sq  * (1.0f/D_MODEL) - mu*mu;
  float rstd = rsqrtf(var + 1e-5f);
  float4 gv = *(const float4*)(gam + d);
  float4 bv = *(const float4*)(bet + d);
  _Float16* o = out + (size_t)row*D_MODEL + d;
  o[0] = (_Float16)((v.x-mu)*rstd*gv.x + bv.x);
  o[1] = (_Float16)((v.y-mu)*rstd*gv.y + bv.y);
  o[2] = (_Float16)((v.z-mu)*rstd*gv.z + bv.z);
  o[3] = (_Float16)((v.w-mu)*rstd*gv.w + bv.w);
}

// ---------------- attention (per b,h block), K stored transposed in LDS ----------------
__global__ __launch_bounds__(256) void attn_kernel(
    const _Float16* __restrict__ qkv, _Float16* __restrict__ attn_o)
{
  __shared__ float qs[TT*DH];
  __shared__ float ks_t[DH*67];     // [d2][kj], stride 67 (gcd(67,32)=1 -> conflict-free)
  __shared__ float vs[TT*DH];
  __shared__ float sc[TT*67];
  int bh = blockIdx.x; int b = bh >> 4, h = bh & 15;
  int tid = threadIdx.x;
  const _Float16* base = qkv + (size_t)b*TT*3072 + h*DH;
  for (int i = tid; i < TT*DH; i += 256) {
    int t = i >> 6, d2 = i & 63;
    const _Float16* rp = base + (size_t)t*3072 + d2;
    qs[i] = (float)rp[0];
    ks_t[d2*67 + t] = (float)rp[1024];
    vs[i] = (float)rp[2048];
  }
  __syncthreads();
  for (int p = tid; p < TT*TT; p += 256) {
    int qi = p / TT, kj = p % TT;
    float s;
    if (qi >= MEM_LEN && kj >= MEM_LEN && kj > qi) {
      s = -1e9f;
    } else {
      float acc = 0.f;
      const float* qr = qs + qi*DH;
      #pragma unroll 8
      for (int d2 = 0; d2 < DH; d2++) acc += qr[d2]*ks_t[d2*67 + kj];
      s = acc * 0.125f;   // 1/sqrt(64)
    }
    sc[qi*67 + kj] = s;
  }
  __syncthreads();
  if (tid < TT) {
    float* r = sc + tid*67;
    float m = -1e30f;
    for (int j = 0; j < TT; j++) m = fmaxf(m, r[j]);
    float ssum = 0.f;
    for (int j = 0; j < TT; j++) { float e = __expf(r[j]-m); r[j] = e; ssum += e; }
    float inv = 1.f/ssum;
    for (int j = 0; j < TT; j++) r[j] *= inv;
  }
  __syncthreads();
  for (int p = tid; p < TT*DH; p += 256) {
    int qi = p >> 6, d2 = p & 63;
    float acc = 0.f;
    const float* ar = sc + qi*67;
    for (int kj = 0; kj < TT; kj++) acc += ar[kj]*vs[kj*DH + d2];
    attn_o[((size_t)b*TT + qi)*D_MODEL + h*DH + d2] = (_Float16)acc;
  }
}

// ---------------- finalize+reduce: z + b2 + p0 + p1 -> enc_out / mem / memcand ----------------
__global__ __launch_bounds__(256) void finalize_reduce(
    const float* __restrict__ z, const float* __restrict__ p0, const float* __restrict__ p1,
    const float* __restrict__ b2,
    float* __restrict__ enc_out, float* __restrict__ mem,
    _Float16* __restrict__ mcb, float* __restrict__ mcf, int chunk)
{
  int row = blockIdx.x; int b = row / TT, t = row % TT;
  int d = threadIdx.x * 4;
  size_t idx = (size_t)row*D_MODEL + d;
  float4 v  = *(const float4*)(z  + idx);
  float4 a0 = *(const float4*)(p0 + idx);
  float4 a1 = *(const float4*)(p1 + idx);
  float4 bv = *(const float4*)(b2 + d);
  v.x += a0.x + a1.x + bv.x;
  v.y += a0.y + a1.y + bv.y;
  v.z += a0.z + a1.z + bv.z;
  v.w += a0.w + a1.w + bv.w;
  if (t >= MEM_LEN) {
    size_t o = ((size_t)b*LL + chunk*CHUNK_LEN + (t - MEM_LEN))*D_MODEL + d;
    *(float4*)(enc_out + o) = v;
  } else {
    size_t mrow = (size_t)b*MEM_LEN + t;
    if (chunk == 0) {
      *(float4*)(mem + mrow*D_MODEL + d) = v;
    } else {
      *(float4*)(mcf + mrow*D_MODEL + d) = v;
      _Float16* o = mcb + mrow*D_MODEL + d;
      o[0] = (_Float16)v.x;
      o[1] = (_Float16)v.y;
      o[2] = (_Float16)v.z;
      o[3] = (_Float16)v.w;
    }
  }
}

// ---------------- copy mem -> output tail ----------------
__global__ __launch_bounds__(256) void copy_mem_kernel(const float* __restrict__ mem,
                                                       float* __restrict__ out) {
  int i = (blockIdx.x * 256 + threadIdx.x) * 4;
  float4 v = *(const float4*)(mem + i);
  *(float4*)(out + i) = v;
}

// ---------------- GEMM: C = A(MxK_total) @ Bw(NxK_total)^T, fp16 in / f32 acc ----------------
#define EPI_QKV   0
#define EPI_RESID 1
#define EPI_RELU  2
#define EPI_PART  3   // split-K partial: write raw acc (no bias) to p0/p1 per blockIdx.z

#define KSLICE 2048

template<int EPI>
__global__ __launch_bounds__(256) void gemm_bt(
    const _Float16* __restrict__ A,
    const _Float16* __restrict__ Bw,
    const float* __restrict__ bias,
    float* __restrict__ zres,      // EPI_RESID: residual; EPI_PART: partial 0
    _Float16* __restrict__ obf,
    float* __restrict__ p1,        // EPI_PART: partial 1
    int K, int lda, int ldo)
{
  __shared__ short As[128*32];
  __shared__ short Bs[128*32];
  int tid = threadIdx.x;
  int lane = tid & 63, wave = tid >> 6;
  int wr = wave >> 1, wc = wave & 1;
  int tm = blockIdx.y * 128, tn = blockIdx.x * 128;
  f32x4 acc[4][4] = {};
  const short* Ash = (const short*)A;
  const short* Bsh = (const short*)Bw;
  if constexpr (EPI == EPI_PART) {
    Ash += (size_t)blockIdx.z * KSLICE;
    Bsh += (size_t)blockIdx.z * KSLICE;
  }
  int e0 = tid * 8;
  int r0 = e0 >> 5, c0 = e0 & 31;

  for (int kt = 0; kt < K; kt += 32) {
    gload16(Ash + (size_t)(tm +      r0)*lda + kt + c0, (char*)As +        wave*1024);
    gload16(Ash + (size_t)(tm + 64 + r0)*lda + kt + c0, (char*)As + 4096 + wave*1024);
    gload16(Bsh + (size_t)(tn +      r0)*lda + kt + c0, (char*)Bs +        wave*1024);
    gload16(Bsh + (size_t)(tn + 64 + r0)*lda + kt + c0, (char*)Bs + 4096 + wave*1024);
    __syncthreads();
    half8_t af[4], bfr[4];
    int ko = (lane >> 4) * 8;
    int rr = lane & 15;
    #pragma unroll
    for (int m = 0; m < 4; m++)
      af[m] = *(const half8_t*)(As + (wr*64 + m*16 + rr)*32 + ko);
    #pragma unroll
    for (int n = 0; n < 4; n++)
      bfr[n] = *(const half8_t*)(Bs + (wc*64 + n*16 + rr)*32 + ko);
    #pragma unroll
    for (int m = 0; m < 4; m++)
      #pragma unroll
      for (int n = 0; n < 4; n++)
        acc[m][n] = __builtin_amdgcn_mfma_f32_16x16x32_f16(af[m], bfr[n], acc[m][n], 0, 0, 0);
    __syncthreads();
  }

  int rbase = tm + wr*64 + ((lane >> 4) << 2);
  int cbase = tn + wc*64 + (lane & 15);
  float* pp = nullptr;
  if constexpr (EPI == EPI_PART) pp = (blockIdx.z == 0) ? zres : p1;
  #pragma unroll
  for (int n = 0; n < 4; n++) {
    int col = cbase + n*16;
    float bs = (EPI == EPI_PART) ? 0.f : bias[col];
    #pragma unroll
    for (int m = 0; m < 4; m++) {
      #pragma unroll
      for (int i = 0; i < 4; i++) {
        int r = rbase + m*16 + i;
        float v = acc[m][n][i] + bs;
        if constexpr (EPI == EPI_QKV) {
          obf[(size_t)r*ldo + col] = (_Float16)v;
        } else if constexpr (EPI == EPI_RESID) {
          zres[(size_t)r*D_MODEL + col] += v;
        } else if constexpr (EPI == EPI_RELU) {
          obf[(size_t)r*ldo + col] = (_Float16)fmaxf(v, 0.f);
        } else { // EPI_PART
          pp[(size_t)r*D_MODEL + col] = v;
        }
      }
    }
  }
}

// ---------------- gate GEMM: 64x64 tiles, M=N=K=1024, sigmoid + mem blend ----------------
__global__ __launch_bounds__(256) void gemm_gate64(
    const _Float16* __restrict__ A,    // mem candidate fp16 [1024][1024]
    const _Float16* __restrict__ Bw,   // w_gate fp16 [1024][1024]
    const float* __restrict__ bias,
    const float* __restrict__ mcf,     // mem candidate fp32
    float* __restrict__ mem)           // in/out
{
  __shared__ short As[64*32];
  __shared__ short Bs[64*32];
  int tid = threadIdx.x;
  int lane = tid & 63, wave = tid >> 6;
  int wr = wave >> 1, wc = wave & 1;
  int tm = blockIdx.y * 64, tn = blockIdx.x * 64;
  f32x4 acc[2][2] = {};
  const short* Ash = (const short*)A;
  const short* Bsh = (const short*)Bw;
  int e0 = tid * 8;
  int r0 = e0 >> 5, c0 = e0 & 31;

  for (int kt = 0; kt < 1024; kt += 32) {
    gload16(Ash + (size_t)(tm + r0)*1024 + kt + c0, (char*)As + wave*1024);
    gload16(Bsh + (size_t)(tn + r0)*1024 + kt + c0, (char*)Bs + wave*1024);
    __syncthreads();
    half8_t af[2], bfr[2];
    int ko = (lane >> 4) * 8;
    int rr = lane & 15;
    #pragma unroll
    for (int m = 0; m < 2; m++)
      af[m] = *(const half8_t*)(As + (wr*32 + m*16 + rr)*32 + ko);
    #pragma unroll
    for (int n = 0; n < 2; n++)
      bfr[n] = *(const half8_t*)(Bs + (wc*32 + n*16 + rr)*32 + ko);
    #pragma unroll
    for (int m = 0; m < 2; m++)
      #pragma unroll
      for (int n = 0; n < 2; n++)
        acc[m][n] = __builtin_amdgcn_mfma_f32_16x16x32_f16(af[m], bfr[n], acc[m][n], 0, 0, 0);
    __syncthreads();
  }

  int rbase = tm + wr*32 + ((lane >> 4) << 2);
  int cbase = tn + wc*32 + (lane & 15);
  #pragma unroll
  for (int n = 0; n < 2; n++) {
    int col = cbase + n*16;
    float bs = bias[col];
    #pragma unroll
    for (int m = 0; m < 2; m++) {
      #pragma unroll
      for (int i = 0; i < 4; i++) {
        int r = rbase + m*16 + i;
        float g = 1.f / (1.f + __expf(-(acc[m][n][i] + bs)));
        size_t mi = (size_t)r*D_MODEL + col;
        mem[mi] = g*mcf[mi] + (1.f - g)*mem[mi];
      }
    }
  }
}

extern "C" void kernel_launch(void* const* d_in, const int* in_sizes, int n_in,
                              void* d_out, int out_size, void* d_ws, size_t ws_size,
                              hipStream_t stream) {
  const int*   in_prob  = (const int*)d_in[0];
  const int*   in_skill = (const int*)d_in[1];
  const float* emb_p    = (const float*)d_in[2];
  const float* emb_s    = (const float*)d_in[3];
  const float* mem_init = (const float*)d_in[4];
  const float* pos      = (const float*)d_in[5];
  const float* w_qkv    = (const float*)d_in[6];
  const float* b_qkv    = (const float*)d_in[7];
  const float* w_out    = (const float*)d_in[8];
  const float* b_out    = (const float*)d_in[9];
  const float* w1       = (const float*)d_in[10];
  const float* b1       = (const float*)d_in[11];
  const float* w2       = (const float*)d_in[12];
  const float* b2       = (const float*)d_in[13];
  const float* g_attn   = (const float*)d_in[14];
  const float* be_attn  = (const float*)d_in[15];
  const float* g_ffn    = (const float*)d_in[16];
  const float* be_ffn   = (const float*)d_in[17];
  const float* w_gate   = (const float*)d_in[18];
  const float* b_gate   = (const float*)d_in[19];

  float* enc_out = (float*)d_out;
  float* mem_out = enc_out + (size_t)BB*LL*D_MODEL;

  char* ws = (char*)d_ws;
  size_t off = 0;
  auto alloc = [&](size_t bytes) -> char* {
    char* p = ws + off;
    off += (bytes + 255) & ~(size_t)255;
    return p;
  };
  _Float16* wqkv_h = (_Float16*)alloc((size_t)3072*1024*2);
  _Float16* wout_h = (_Float16*)alloc((size_t)1024*1024*2);
  _Float16* w1_h   = (_Float16*)alloc((size_t)4096*1024*2);
  _Float16* w2_h   = (_Float16*)alloc((size_t)1024*4096*2);
  _Float16* wgate_h= (_Float16*)alloc((size_t)1024*1024*2);
  float*    z      = (float*)alloc((size_t)MTOK*D_MODEL*4);
  _Float16* zn     = (_Float16*)alloc((size_t)MTOK*D_MODEL*2);
  _Float16* qkv    = (_Float16*)alloc((size_t)MTOK*3072*2);
  _Float16* ao     = (_Float16*)alloc((size_t)MTOK*D_MODEL*2);
  _Float16* hb     = (_Float16*)alloc((size_t)MTOK*D_MODEL*2);
  _Float16* fh     = (_Float16*)alloc((size_t)MTOK*4096*2);
  _Float16* mcb    = (_Float16*)alloc((size_t)1024*1024*2);
  float*    mem    = (float*)alloc((size_t)1024*1024*4);
  float*    mcf    = (float*)alloc((size_t)1024*1024*4);
  float*    part0  = (float*)alloc((size_t)MTOK*D_MODEL*4);
  float*    part1  = (float*)alloc((size_t)MTOK*D_MODEL*4);
  if (off > ws_size) return;  // workspace too small -> fail loudly via wrong output

  // weights -> fp16 (cheap, once per call)
  f2h_kernel<<<(3072*1024)/1024, 256, 0, stream>>>(w_qkv, wqkv_h, 3072*1024);
  f2h_kernel<<<(1024*1024)/1024, 256, 0, stream>>>(w_out, wout_h, 1024*1024);
  f2h_kernel<<<(4096*1024)/1024, 256, 0, stream>>>(w1, w1_h, 4096*1024);
  f2h_kernel<<<(1024*4096)/1024, 256, 0, stream>>>(w2, w2_h, 1024*4096);
  f2h_kernel<<<(1024*1024)/1024, 256, 0, stream>>>(w_gate, wgate_h, 1024*1024);

  for (int c = 0; c < NCHUNK; c++) {
    const float* msrc = (c == 0) ? mem_init : mem;
    int mbs = (c == 0) ? 0 : MEM_LEN*D_MODEL;
    build_z_ln<<<MTOK, 256, 0, stream>>>(in_prob, in_skill, emb_p, emb_s,
                                         msrc, mbs, pos, g_attn, be_attn, z, zn, c);
    gemm_bt<EPI_QKV><<<dim3(3072/128, MTOK/128), 256, 0, stream>>>(
        zn, wqkv_h, b_qkv, nullptr, qkv, nullptr, 1024, 1024, 3072);
    attn_kernel<<<BB*N_HEADS, 256, 0, stream>>>(qkv, ao);
    gemm_bt<EPI_RESID><<<dim3(1024/128, MTOK/128), 256, 0, stream>>>(
        ao, wout_h, b_out, z, nullptr, nullptr, 1024, 1024, 1024);
    ln_kernel<<<MTOK, 256, 0, stream>>>(z, g_ffn, be_ffn, hb);
    gemm_bt<EPI_RELU><<<dim3(4096/128, MTOK/128), 256, 0, stream>>>(
        hb, w1_h, b1, nullptr, fh, nullptr, 1024, 1024, 4096);
    // FFN2 split-K=2: each z-slice covers K=2048 of 4096
    gemm_bt<EPI_PART><<<dim3(1024/128, MTOK/128, 2), 256, 0, stream>>>(
        fh, w2_h, b2, part0, nullptr, part1, KSLICE, 4096, 1024);
    finalize_reduce<<<MTOK, 256, 0, stream>>>(z, part0, part1, b2,
                                              enc_out, mem, mcb, mcf, c);
    if (c > 0) {
      gemm_gate64<<<dim3(1024/64, 1024/64), 256, 0, stream>>>(
          mcb, wgate_h, b_gate, mcf, mem);
    }
  }
  copy_mem_kernel<<<(1024*1024)/1024, 256, 0, stream>>>(mem, mem_out);
}

// Round 4
// 11977.770 us; speedup vs baseline: 1.4331x; 1.0814x over previous
//
#include <hip/hip_runtime.h>
#include <hip/hip_bf16.h>

#define D_MODEL 1024
#define N_HEADS 16
#define DH 64
#define CHUNK_LEN 50
#define MEM_LEN 16
#define TT 66            // MEM_LEN + CHUNK_LEN
#define BB 64
#define LL 2000
#define NCHUNK 40
#define MTOK (BB*TT)     // 4224

typedef _Float16 half8_t __attribute__((ext_vector_type(8)));
typedef __attribute__((ext_vector_type(4))) float f32x4;

typedef __attribute__((address_space(1))) const void GVoid;
typedef __attribute__((address_space(3))) void LVoid;

__device__ __forceinline__ void gload16(const void* g, void* l) {
  __builtin_amdgcn_global_load_lds((GVoid*)g, (LVoid*)l, 16, 0, 0);
}

// ---------------- weight fp32 -> fp16 ----------------
__global__ __launch_bounds__(256) void f2h_kernel(const float* __restrict__ in,
                                                  _Float16* __restrict__ out, int n) {
  int i = (blockIdx.x * 256 + threadIdx.x) * 4;
  if (i < n) {
    float4 v = *(const float4*)(in + i);
    out[i+0] = (_Float16)v.x;
    out[i+1] = (_Float16)v.y;
    out[i+2] = (_Float16)v.z;
    out[i+3] = (_Float16)v.w;
  }
}

// ---------------- build z (gather + mem + pos) fused with LN1 ----------------
__global__ __launch_bounds__(256) void build_z_ln(
    const int* __restrict__ in_prob, const int* __restrict__ in_skill,
    const float* __restrict__ emb_p, const float* __restrict__ emb_s,
    const float* __restrict__ mem_src, int mem_bstride,
    const float* __restrict__ pos,
    const float* __restrict__ gam, const float* __restrict__ bet,
    float* __restrict__ z, _Float16* __restrict__ zn, int chunk)
{
  int row = blockIdx.x;                 // 0..MTOK-1
  int b = row / TT, t = row % TT;
  int tid = threadIdx.x;
  int d = tid * 4;
  float4 v;
  if (t < MEM_LEN) {
    v = *(const float4*)(mem_src + (size_t)b*mem_bstride + t*D_MODEL + d);
  } else {
    int tok = chunk*CHUNK_LEN + (t - MEM_LEN);
    int p = in_prob[b*LL + tok];
    int s = in_skill[b*LL + tok];
    float4 vp = *(const float4*)(emb_p + (size_t)p*D_MODEL + d);
    float4 vs = *(const float4*)(emb_s + (size_t)s*D_MODEL + d);
    v = make_float4(vp.x+vs.x, vp.y+vs.y, vp.z+vs.z, vp.w+vs.w);
  }
  float4 pv = *(const float4*)(pos + t*D_MODEL + d);
  v.x += pv.x; v.y += pv.y; v.z += pv.z; v.w += pv.w;
  *(float4*)(z + (size_t)row*D_MODEL + d) = v;
  // LN over the row
  float sum = v.x+v.y+v.z+v.w;
  float sq  = v.x*v.x+v.y*v.y+v.z*v.z+v.w*v.w;
  #pragma unroll
  for (int off = 32; off; off >>= 1) {
    sum += __shfl_down(sum, off, 64);
    sq  += __shfl_down(sq,  off, 64);
  }
  __shared__ float rs_[4], rq_[4];
  int wave = tid >> 6, lane = tid & 63;
  if (lane == 0) { rs_[wave] = sum; rq_[wave] = sq; }
  __syncthreads();
  sum = rs_[0]+rs_[1]+rs_[2]+rs_[3];
  sq  = rq_[0]+rq_[1]+rq_[2]+rq_[3];
  float mu  = sum * (1.0f/D_MODEL);
  float var = sq  * (1.0f/D_MODEL) - mu*mu;
  float rstd = rsqrtf(var + 1e-5f);
  float4 gv = *(const float4*)(gam + d);
  float4 bv = *(const float4*)(bet + d);
  _Float16* o = zn + (size_t)row*D_MODEL + d;
  o[0] = (_Float16)((v.x-mu)*rstd*gv.x + bv.x);
  o[1] = (_Float16)((v.y-mu)*rstd*gv.y + bv.y);
  o[2] = (_Float16)((v.z-mu)*rstd*gv.z + bv.z);
  o[3] = (_Float16)((v.w-mu)*rstd*gv.w + bv.w);
}

// ---------------- plain LN (z fp32 -> fp16 out) ----------------
__global__ __launch_bounds__(256) void ln_kernel(
    const float* __restrict__ z, const float* __restrict__ gam, const float* __restrict__ bet,
    _Float16* __restrict__ out)
{
  int row = blockIdx.x;
  int tid = threadIdx.x;
  int d = tid * 4;
  float4 v = *(const float4*)(z + (size_t)row*D_MODEL + d);
  float sum = v.x+v.y+v.z+v.w;
  float sq  = v.x*v.x+v.y*v.y+v.z*v.z+v.w*v.w;
  #pragma unroll
  for (int off = 32; off; off >>= 1) {
    sum += __shfl_down(sum, off, 64);
    sq  += __shfl_down(sq,  off, 64);
  }
  __shared__ float rs_[4], rq_[4];
  int wave = tid >> 6, lane = tid & 63;
  if (lane == 0) { rs_[wave] = sum; rq_[wave] = sq; }
  __syncthreads();
  sum = rs_[0]+rs_[1]+rs_[2]+rs_[3];
  sq  = rq_[0]+rq_[1]+rq_[2]+rq_[3];
  float mu  = sum * (1.0f/D_MODEL);
  float var = sq  * (1.0f/D_MODEL) - mu*mu;
  float rstd = rsqrtf(var + 1e-5f);
  float4 gv = *(const float4*)(gam + d);
  float4 bv = *(const float4*)(bet + d);
  _Float16* o = out + (size_t)row*D_MODEL + d;
  o[0] = (_Float16)((v.x-mu)*rstd*gv.x + bv.x);
  o[1] = (_Float16)((v.y-mu)*rstd*gv.y + bv.y);
  o[2] = (_Float16)((v.z-mu)*rstd*gv.z + bv.z);
  o[3] = (_Float16)((v.w-mu)*rstd*gv.w + bv.w);
}

// ---------------- attention (per b,h block), register-tiled ----------------
// Qt/Kt in LDS transposed [d2][t] stride 68 (float4-readable, pad +8 tail).
// scores: thread tile 4qi x 8kj (153 threads). PV: thread tile 4qi x 8d2 (136 threads).
__global__ __launch_bounds__(256) void attn_kernel(
    const _Float16* __restrict__ qkv, _Float16* __restrict__ attn_o)
{
  __shared__ float qs_t[64*68 + 8];
  __shared__ float ks_t[64*68 + 8];
  __shared__ float vs[TT*DH];
  __shared__ float sc[TT*67];
  int bh = blockIdx.x; int b = bh >> 4, h = bh & 15;
  int tid = threadIdx.x;
  const _Float16* base = qkv + (size_t)b*TT*3072 + h*DH;
  for (int i = tid; i < TT*DH; i += 256) {
    int t = i >> 6, d2 = i & 63;
    const _Float16* rp = base + (size_t)t*3072 + d2;
    qs_t[d2*68 + t] = (float)rp[0];
    ks_t[d2*68 + t] = (float)rp[1024];
    vs[t*64 + d2]   = (float)rp[2048];
  }
  __syncthreads();
  // ---- scores: S[qi][kj] = (Q.K)/8 with causal mask ----
  if (tid < 153) {
    int ti = tid / 9, tj = tid % 9;          // ti 0..16, tj 0..8
    int qi0 = ti*4, kj0 = tj*8;
    float acc[4][8];
    #pragma unroll
    for (int i = 0; i < 4; i++)
      #pragma unroll
      for (int j = 0; j < 8; j++) acc[i][j] = 0.f;
    for (int d2 = 0; d2 < 64; d2++) {
      float4 qv = *(const float4*)(qs_t + d2*68 + qi0);
      float4 k0 = *(const float4*)(ks_t + d2*68 + kj0);
      float4 k1 = *(const float4*)(ks_t + d2*68 + kj0 + 4);
      float q_[4] = {qv.x, qv.y, qv.z, qv.w};
      float k_[8] = {k0.x, k0.y, k0.z, k0.w, k1.x, k1.y, k1.z, k1.w};
      #pragma unroll
      for (int i = 0; i < 4; i++)
        #pragma unroll
        for (int j = 0; j < 8; j++)
          acc[i][j] += q_[i]*k_[j];
    }
    #pragma unroll
    for (int i = 0; i < 4; i++) {
      int qi = qi0 + i;
      if (qi >= TT) continue;
      #pragma unroll
      for (int j = 0; j < 8; j++) {
        int kj = kj0 + j;
        if (kj >= TT) continue;
        float s;
        if (qi >= MEM_LEN && kj >= MEM_LEN && kj > qi) s = -1e9f;
        else s = acc[i][j]*0.125f;
        sc[qi*67 + kj] = s;
      }
    }
  }
  __syncthreads();
  if (tid < TT) {
    float* r = sc + tid*67;
    float m = -1e30f;
    for (int j = 0; j < TT; j++) m = fmaxf(m, r[j]);
    float ssum = 0.f;
    for (int j = 0; j < TT; j++) { float e = __expf(r[j]-m); r[j] = e; ssum += e; }
    float inv = 1.f/ssum;
    for (int j = 0; j < TT; j++) r[j] *= inv;
  }
  __syncthreads();
  // ---- PV: O[qi][d2] = sum_kj P[qi][kj] * V[kj][d2] ----
  if (tid < 136) {
    int ti = tid >> 3, tj = tid & 7;         // ti 0..16, tj 0..7
    int qi0 = ti*4, d20 = tj*8;
    float acc[4][8];
    #pragma unroll
    for (int i = 0; i < 4; i++)
      #pragma unroll
      for (int j = 0; j < 8; j++) acc[i][j] = 0.f;
    for (int kj = 0; kj < TT; kj++) {
      float a_[4];
      #pragma unroll
      for (int i = 0; i < 4; i++)
        a_[i] = (qi0 + i < TT) ? sc[(qi0+i)*67 + kj] : 0.f;
      float4 v0 = *(const float4*)(vs + kj*64 + d20);
      float4 v1 = *(const float4*)(vs + kj*64 + d20 + 4);
      float v_[8] = {v0.x, v0.y, v0.z, v0.w, v1.x, v1.y, v1.z, v1.w};
      #pragma unroll
      for (int i = 0; i < 4; i++)
        #pragma unroll
        for (int j = 0; j < 8; j++)
          acc[i][j] += a_[i]*v_[j];
    }
    #pragma unroll
    for (int i = 0; i < 4; i++) {
      int qi = qi0 + i;
      if (qi >= TT) continue;
      _Float16* o = attn_o + ((size_t)b*TT + qi)*D_MODEL + h*DH + d20;
      #pragma unroll
      for (int j = 0; j < 8; j++) o[j] = (_Float16)acc[i][j];
    }
  }
}

// ---------------- finalize+reduce: z + b2 + p0 + p1 -> enc_out / mem / memcand ----------------
__global__ __launch_bounds__(256) void finalize_reduce(
    const float* __restrict__ z, const float* __restrict__ p0, const float* __restrict__ p1,
    const float* __restrict__ b2,
    float* __restrict__ enc_out, float* __restrict__ mem,
    _Float16* __restrict__ mcb, float* __restrict__ mcf, int chunk)
{
  int row = blockIdx.x; int b = row / TT, t = row % TT;
  int d = threadIdx.x * 4;
  size_t idx = (size_t)row*D_MODEL + d;
  float4 v  = *(const float4*)(z  + idx);
  float4 a0 = *(const float4*)(p0 + idx);
  float4 a1 = *(const float4*)(p1 + idx);
  float4 bv = *(const float4*)(b2 + d);
  v.x += a0.x + a1.x + bv.x;
  v.y += a0.y + a1.y + bv.y;
  v.z += a0.z + a1.z + bv.z;
  v.w += a0.w + a1.w + bv.w;
  if (t >= MEM_LEN) {
    size_t o = ((size_t)b*LL + chunk*CHUNK_LEN + (t - MEM_LEN))*D_MODEL + d;
    *(float4*)(enc_out + o) = v;
  } else {
    size_t mrow = (size_t)b*MEM_LEN + t;
    if (chunk == 0) {
      *(float4*)(mem + mrow*D_MODEL + d) = v;
    } else {
      *(float4*)(mcf + mrow*D_MODEL + d) = v;
      _Float16* o = mcb + mrow*D_MODEL + d;
      o[0] = (_Float16)v.x;
      o[1] = (_Float16)v.y;
      o[2] = (_Float16)v.z;
      o[3] = (_Float16)v.w;
    }
  }
}

// ---------------- copy mem -> output tail ----------------
__global__ __launch_bounds__(256) void copy_mem_kernel(const float* __restrict__ mem,
                                                       float* __restrict__ out) {
  int i = (blockIdx.x * 256 + threadIdx.x) * 4;
  float4 v = *(const float4*)(mem + i);
  *(float4*)(out + i) = v;
}

// ---------------- GEMM: C = A(MxK_total) @ Bw(NxK_total)^T, fp16 in / f32 acc ----------------
// 2-phase double-buffered pipeline: STAGE(next) issued before compute(cur),
// one __syncthreads per K-step (its implicit vmcnt/lgkm drain guarantees buf ready).
#define EPI_QKV   0
#define EPI_RESID 1
#define EPI_RELU  2
#define EPI_PART  3   // split-K partial: write raw acc (no bias) to p0/p1 per blockIdx.z

#define KSLICE 2048

template<int EPI>
__global__ __launch_bounds__(256) void gemm_bt(
    const _Float16* __restrict__ A,
    const _Float16* __restrict__ Bw,
    const float* __restrict__ bias,
    float* __restrict__ zres,      // EPI_RESID: residual; EPI_PART: partial 0
    _Float16* __restrict__ obf,
    float* __restrict__ p1,        // EPI_PART: partial 1
    int K, int lda, int ldo)
{
  __shared__ short As[2][128*32];
  __shared__ short Bs[2][128*32];
  int tid = threadIdx.x;
  int lane = tid & 63, wave = tid >> 6;
  int wr = wave >> 1, wc = wave & 1;
  int tm = blockIdx.y * 128, tn = blockIdx.x * 128;
  f32x4 acc[4][4] = {};
  const short* Ash = (const short*)A;
  const short* Bsh = (const short*)Bw;
  if constexpr (EPI == EPI_PART) {
    Ash += (size_t)blockIdx.z * KSLICE;
    Bsh += (size_t)blockIdx.z * KSLICE;
  }
  int e0 = tid * 8;
  int r0 = e0 >> 5, c0 = e0 & 31;
  int ko = (lane >> 4) * 8;
  int rr = lane & 15;

  auto STAGE = [&](int buf, int kt) {
    gload16(Ash + (size_t)(tm +      r0)*lda + kt + c0, (char*)&As[buf][0] +        wave*1024);
    gload16(Ash + (size_t)(tm + 64 + r0)*lda + kt + c0, (char*)&As[buf][0] + 4096 + wave*1024);
    gload16(Bsh + (size_t)(tn +      r0)*lda + kt + c0, (char*)&Bs[buf][0] +        wave*1024);
    gload16(Bsh + (size_t)(tn + 64 + r0)*lda + kt + c0, (char*)&Bs[buf][0] + 4096 + wave*1024);
  };
  auto COMPUTE = [&](int buf) {
    half8_t af[4], bfr[4];
    #pragma unroll
    for (int m = 0; m < 4; m++)
      af[m] = *(const half8_t*)(&As[buf][(wr*64 + m*16 + rr)*32 + ko]);
    #pragma unroll
    for (int n = 0; n < 4; n++)
      bfr[n] = *(const half8_t*)(&Bs[buf][(wc*64 + n*16 + rr)*32 + ko]);
    #pragma unroll
    for (int m = 0; m < 4; m++)
      #pragma unroll
      for (int n = 0; n < 4; n++)
        acc[m][n] = __builtin_amdgcn_mfma_f32_16x16x32_f16(af[m], bfr[n], acc[m][n], 0, 0, 0);
  };

  STAGE(0, 0);
  __syncthreads();
  int cur = 0;
  for (int kt = 32; kt < K; kt += 32) {
    STAGE(cur ^ 1, kt);
    COMPUTE(cur);
    __syncthreads();       // drains vmcnt(0) lgkmcnt(0): next buf staged, cur buf free
    cur ^= 1;
  }
  COMPUTE(cur);

  int rbase = tm + wr*64 + ((lane >> 4) << 2);
  int cbase = tn + wc*64 + (lane & 15);
  float* pp = nullptr;
  if constexpr (EPI == EPI_PART) pp = (blockIdx.z == 0) ? zres : p1;
  #pragma unroll
  for (int n = 0; n < 4; n++) {
    int col = cbase + n*16;
    float bs = (EPI == EPI_PART) ? 0.f : bias[col];
    #pragma unroll
    for (int m = 0; m < 4; m++) {
      #pragma unroll
      for (int i = 0; i < 4; i++) {
        int r = rbase + m*16 + i;
        float v = acc[m][n][i] + bs;
        if constexpr (EPI == EPI_QKV) {
          obf[(size_t)r*ldo + col] = (_Float16)v;
        } else if constexpr (EPI == EPI_RESID) {
          zres[(size_t)r*D_MODEL + col] += v;
        } else if constexpr (EPI == EPI_RELU) {
          obf[(size_t)r*ldo + col] = (_Float16)fmaxf(v, 0.f);
        } else { // EPI_PART
          pp[(size_t)r*D_MODEL + col] = v;
        }
      }
    }
  }
}

// ---------------- gate GEMM: 64x64 tiles, M=N=K=1024, sigmoid + mem blend ----------------
__global__ __launch_bounds__(256) void gemm_gate64(
    const _Float16* __restrict__ A,    // mem candidate fp16 [1024][1024]
    const _Float16* __restrict__ Bw,   // w_gate fp16 [1024][1024]
    const float* __restrict__ bias,
    const float* __restrict__ mcf,     // mem candidate fp32
    float* __restrict__ mem)           // in/out
{
  __shared__ short As[64*32];
  __shared__ short Bs[64*32];
  int tid = threadIdx.x;
  int lane = tid & 63, wave = tid >> 6;
  int wr = wave >> 1, wc = wave & 1;
  int tm = blockIdx.y * 64, tn = blockIdx.x * 64;
  f32x4 acc[2][2] = {};
  const short* Ash = (const short*)A;
  const short* Bsh = (const short*)Bw;
  int e0 = tid * 8;
  int r0 = e0 >> 5, c0 = e0 & 31;

  for (int kt = 0; kt < 1024; kt += 32) {
    gload16(Ash + (size_t)(tm + r0)*1024 + kt + c0, (char*)As + wave*1024);
    gload16(Bsh + (size_t)(tn + r0)*1024 + kt + c0, (char*)Bs + wave*1024);
    __syncthreads();
    half8_t af[2], bfr[2];
    int ko = (lane >> 4) * 8;
    int rr = lane & 15;
    #pragma unroll
    for (int m = 0; m < 2; m++)
      af[m] = *(const half8_t*)(As + (wr*32 + m*16 + rr)*32 + ko);
    #pragma unroll
    for (int n = 0; n < 2; n++)
      bfr[n] = *(const half8_t*)(Bs + (wc*32 + n*16 + rr)*32 + ko);
    #pragma unroll
    for (int m = 0; m < 2; m++)
      #pragma unroll
      for (int n = 0; n < 2; n++)
        acc[m][n] = __builtin_amdgcn_mfma_f32_16x16x32_f16(af[m], bfr[n], acc[m][n], 0, 0, 0);
    __syncthreads();
  }

  int rbase = tm + wr*32 + ((lane >> 4) << 2);
  int cbase = tn + wc*32 + (lane & 15);
  #pragma unroll
  for (int n = 0; n < 2; n++) {
    int col = cbase + n*16;
    float bs = bias[col];
    #pragma unroll
    for (int m = 0; m < 2; m++) {
      #pragma unroll
      for (int i = 0; i < 4; i++) {
        int r = rbase + m*16 + i;
        float g = 1.f / (1.f + __expf(-(acc[m][n][i] + bs)));
        size_t mi = (size_t)r*D_MODEL + col;
        mem[mi] = g*mcf[mi] + (1.f - g)*mem[mi];
      }
    }
  }
}

extern "C" void kernel_launch(void* const* d_in, const int* in_sizes, int n_in,
                              void* d_out, int out_size, void* d_ws, size_t ws_size,
                              hipStream_t stream) {
  const int*   in_prob  = (const int*)d_in[0];
  const int*   in_skill = (const int*)d_in[1];
  const float* emb_p    = (const float*)d_in[2];
  const float* emb_s    = (const float*)d_in[3];
  const float* mem_init = (const float*)d_in[4];
  const float* pos      = (const float*)d_in[5];
  const float* w_qkv    = (const float*)d_in[6];
  const float* b_qkv    = (const float*)d_in[7];
  const float* w_out    = (const float*)d_in[8];
  const float* b_out    = (const float*)d_in[9];
  const float* w1       = (const float*)d_in[10];
  const float* b1       = (const float*)d_in[11];
  const float* w2       = (const float*)d_in[12];
  const float* b2       = (const float*)d_in[13];
  const float* g_attn   = (const float*)d_in[14];
  const float* be_attn  = (const float*)d_in[15];
  const float* g_ffn    = (const float*)d_in[16];
  const float* be_ffn   = (const float*)d_in[17];
  const float* w_gate   = (const float*)d_in[18];
  const float* b_gate   = (const float*)d_in[19];

  float* enc_out = (float*)d_out;
  float* mem_out = enc_out + (size_t)BB*LL*D_MODEL;

  char* ws = (char*)d_ws;
  size_t off = 0;
  auto alloc = [&](size_t bytes) -> char* {
    char* p = ws + off;
    off += (bytes + 255) & ~(size_t)255;
    return p;
  };
  _Float16* wqkv_h = (_Float16*)alloc((size_t)3072*1024*2);
  _Float16* wout_h = (_Float16*)alloc((size_t)1024*1024*2);
  _Float16* w1_h   = (_Float16*)alloc((size_t)4096*1024*2);
  _Float16* w2_h   = (_Float16*)alloc((size_t)1024*4096*2);
  _Float16* wgate_h= (_Float16*)alloc((size_t)1024*1024*2);
  float*    z      = (float*)alloc((size_t)MTOK*D_MODEL*4);
  _Float16* zn     = (_Float16*)alloc((size_t)MTOK*D_MODEL*2);
  _Float16* qkv    = (_Float16*)alloc((size_t)MTOK*3072*2);
  _Float16* ao     = (_Float16*)alloc((size_t)MTOK*D_MODEL*2);
  _Float16* hb     = (_Float16*)alloc((size_t)MTOK*D_MODEL*2);
  _Float16* fh     = (_Float16*)alloc((size_t)MTOK*4096*2);
  _Float16* mcb    = (_Float16*)alloc((size_t)1024*1024*2);
  float*    mem    = (float*)alloc((size_t)1024*1024*4);
  float*    mcf    = (float*)alloc((size_t)1024*1024*4);
  float*    part0  = (float*)alloc((size_t)MTOK*D_MODEL*4);
  float*    part1  = (float*)alloc((size_t)MTOK*D_MODEL*4);
  if (off > ws_size) return;  // workspace too small -> fail loudly via wrong output

  // weights -> fp16 (cheap, once per call)
  f2h_kernel<<<(3072*1024)/1024, 256, 0, stream>>>(w_qkv, wqkv_h, 3072*1024);
  f2h_kernel<<<(1024*1024)/1024, 256, 0, stream>>>(w_out, wout_h, 1024*1024);
  f2h_kernel<<<(4096*1024)/1024, 256, 0, stream>>>(w1, w1_h, 4096*1024);
  f2h_kernel<<<(1024*4096)/1024, 256, 0, stream>>>(w2, w2_h, 1024*4096);
  f2h_kernel<<<(1024*1024)/1024, 256, 0, stream>>>(w_gate, wgate_h, 1024*1024);

  for (int c = 0; c < NCHUNK; c++) {
    const float* msrc = (c == 0) ? mem_init : mem;
    int mbs = (c == 0) ? 0 : MEM_LEN*D_MODEL;
    build_z_ln<<<MTOK, 256, 0, stream>>>(in_prob, in_skill, emb_p, emb_s,
                                         msrc, mbs, pos, g_attn, be_attn, z, zn, c);
    gemm_bt<EPI_QKV><<<dim3(3072/128, MTOK/128), 256, 0, stream>>>(
        zn, wqkv_h, b_qkv, nullptr, qkv, nullptr, 1024, 1024, 3072);
    attn_kernel<<<BB*N_HEADS, 256, 0, stream>>>(qkv, ao);
    gemm_bt<EPI_RESID><<<dim3(1024/128, MTOK/128), 256, 0, stream>>>(
        ao, wout_h, b_out, z, nullptr, nullptr, 1024, 1024, 1024);
    ln_kernel<<<MTOK, 256, 0, stream>>>(z, g_ffn, be_ffn, hb);
    gemm_bt<EPI_RELU><<<dim3(4096/128, MTOK/128), 256, 0, stream>>>(
        hb, w1_h, b1, nullptr, fh, nullptr, 1024, 1024, 4096);
    // FFN2 split-K=2: each z-slice covers K=2048 of 4096
    gemm_bt<EPI_PART><<<dim3(1024/128, MTOK/128, 2), 256, 0, stream>>>(
        fh, w2_h, b2, part0, nullptr, part1, KSLICE, 4096, 1024);
    finalize_reduce<<<MTOK, 256, 0, stream>>>(z, part0, part1, b2,
                                              enc_out, mem, mcb, mcf, c);
    if (c > 0) {
      gemm_gate64<<<dim3(1024/64, 1024/64), 256, 0, stream>>>(
          mcb, wgate_h, b_gate, mcf, mem);
    }
  }
  copy_mem_kernel<<<(1024*1024)/1024, 256, 0, stream>>>(mem, mem_out);
}

// Round 5
// 11549.910 us; speedup vs baseline: 1.4861x; 1.0370x over previous
//
#include <hip/hip_runtime.h>
#include <hip/hip_bf16.h>

#define D_MODEL 1024
#define N_HEADS 16
#define DH 64
#define CHUNK_LEN 50
#define MEM_LEN 16
#define TT 66            // MEM_LEN + CHUNK_LEN
#define BB 64
#define LL 2000
#define NCHUNK 40
#define MTOK (BB*TT)     // 4224

typedef _Float16 half8_t __attribute__((ext_vector_type(8)));
typedef __attribute__((ext_vector_type(4))) float f32x4;

typedef __attribute__((address_space(1))) const void GVoid;
typedef __attribute__((address_space(3))) void LVoid;

__device__ __forceinline__ void gload16(const void* g, void* l) {
  __builtin_amdgcn_global_load_lds((GVoid*)g, (LVoid*)l, 16, 0, 0);
}

// ---------------- weight fp32 -> fp16 ----------------
__global__ __launch_bounds__(256) void f2h_kernel(const float* __restrict__ in,
                                                  _Float16* __restrict__ out, int n) {
  int i = (blockIdx.x * 256 + threadIdx.x) * 4;
  if (i < n) {
    float4 v = *(const float4*)(in + i);
    out[i+0] = (_Float16)v.x;
    out[i+1] = (_Float16)v.y;
    out[i+2] = (_Float16)v.z;
    out[i+3] = (_Float16)v.w;
  }
}

// ---------------- build z (gather + mem + pos) fused with LN1 ----------------
__global__ __launch_bounds__(256) void build_z_ln(
    const int* __restrict__ in_prob, const int* __restrict__ in_skill,
    const float* __restrict__ emb_p, const float* __restrict__ emb_s,
    const float* __restrict__ mem_src, int mem_bstride,
    const float* __restrict__ pos,
    const float* __restrict__ gam, const float* __restrict__ bet,
    float* __restrict__ z, _Float16* __restrict__ zn, int chunk)
{
  int row = blockIdx.x;                 // 0..MTOK-1
  int b = row / TT, t = row % TT;
  int tid = threadIdx.x;
  int d = tid * 4;
  float4 v;
  if (t < MEM_LEN) {
    v = *(const float4*)(mem_src + (size_t)b*mem_bstride + t*D_MODEL + d);
  } else {
    int tok = chunk*CHUNK_LEN + (t - MEM_LEN);
    int p = in_prob[b*LL + tok];
    int s = in_skill[b*LL + tok];
    float4 vp = *(const float4*)(emb_p + (size_t)p*D_MODEL + d);
    float4 vs = *(const float4*)(emb_s + (size_t)s*D_MODEL + d);
    v = make_float4(vp.x+vs.x, vp.y+vs.y, vp.z+vs.z, vp.w+vs.w);
  }
  float4 pv = *(const float4*)(pos + t*D_MODEL + d);
  v.x += pv.x; v.y += pv.y; v.z += pv.z; v.w += pv.w;
  *(float4*)(z + (size_t)row*D_MODEL + d) = v;
  // LN over the row
  float sum = v.x+v.y+v.z+v.w;
  float sq  = v.x*v.x+v.y*v.y+v.z*v.z+v.w*v.w;
  #pragma unroll
  for (int off = 32; off; off >>= 1) {
    sum += __shfl_down(sum, off, 64);
    sq  += __shfl_down(sq,  off, 64);
  }
  __shared__ float rs_[4], rq_[4];
  int wave = tid >> 6, lane = tid & 63;
  if (lane == 0) { rs_[wave] = sum; rq_[wave] = sq; }
  __syncthreads();
  sum = rs_[0]+rs_[1]+rs_[2]+rs_[3];
  sq  = rq_[0]+rq_[1]+rq_[2]+rq_[3];
  float mu  = sum * (1.0f/D_MODEL);
  float var = sq  * (1.0f/D_MODEL) - mu*mu;
  float rstd = rsqrtf(var + 1e-5f);
  float4 gv = *(const float4*)(gam + d);
  float4 bv = *(const float4*)(bet + d);
  _Float16* o = zn + (size_t)row*D_MODEL + d;
  o[0] = (_Float16)((v.x-mu)*rstd*gv.x + bv.x);
  o[1] = (_Float16)((v.y-mu)*rstd*gv.y + bv.y);
  o[2] = (_Float16)((v.z-mu)*rstd*gv.z + bv.z);
  o[3] = (_Float16)((v.w-mu)*rstd*gv.w + bv.w);
}

// ---------------- plain LN (z fp32 -> fp16 out) ----------------
__global__ __launch_bounds__(256) void ln_kernel(
    const float* __restrict__ z, const float* __restrict__ gam, const float* __restrict__ bet,
    _Float16* __restrict__ out)
{
  int row = blockIdx.x;
  int tid = threadIdx.x;
  int d = tid * 4;
  float4 v = *(const float4*)(z + (size_t)row*D_MODEL + d);
  float sum = v.x+v.y+v.z+v.w;
  float sq  = v.x*v.x+v.y*v.y+v.z*v.z+v.w*v.w;
  #pragma unroll
  for (int off = 32; off; off >>= 1) {
    sum += __shfl_down(sum, off, 64);
    sq  += __shfl_down(sq,  off, 64);
  }
  __shared__ float rs_[4], rq_[4];
  int wave = tid >> 6, lane = tid & 63;
  if (lane == 0) { rs_[wave] = sum; rq_[wave] = sq; }
  __syncthreads();
  sum = rs_[0]+rs_[1]+rs_[2]+rs_[3];
  sq  = rq_[0]+rq_[1]+rq_[2]+rq_[3];
  float mu  = sum * (1.0f/D_MODEL);
  float var = sq  * (1.0f/D_MODEL) - mu*mu;
  float rstd = rsqrtf(var + 1e-5f);
  float4 gv = *(const float4*)(gam + d);
  float4 bv = *(const float4*)(bet + d);
  _Float16* o = out + (size_t)row*D_MODEL + d;
  o[0] = (_Float16)((v.x-mu)*rstd*gv.x + bv.x);
  o[1] = (_Float16)((v.y-mu)*rstd*gv.y + bv.y);
  o[2] = (_Float16)((v.z-mu)*rstd*gv.z + bv.z);
  o[3] = (_Float16)((v.w-mu)*rstd*gv.w + bv.w);
}

// ---------------- attention (per b,h block), register-tiled ----------------
__global__ __launch_bounds__(256) void attn_kernel(
    const _Float16* __restrict__ qkv, _Float16* __restrict__ attn_o)
{
  __shared__ float qs_t[64*68 + 8];
  __shared__ float ks_t[64*68 + 8];
  __shared__ float vs[TT*DH];
  __shared__ float sc[TT*67];
  int bh = blockIdx.x; int b = bh >> 4, h = bh & 15;
  int tid = threadIdx.x;
  const _Float16* base = qkv + (size_t)b*TT*3072 + h*DH;
  for (int i = tid; i < TT*DH; i += 256) {
    int t = i >> 6, d2 = i & 63;
    const _Float16* rp = base + (size_t)t*3072 + d2;
    qs_t[d2*68 + t] = (float)rp[0];
    ks_t[d2*68 + t] = (float)rp[1024];
    vs[t*64 + d2]   = (float)rp[2048];
  }
  __syncthreads();
  // ---- scores: S[qi][kj] = (Q.K)/8 with causal mask ----
  if (tid < 153) {
    int ti = tid / 9, tj = tid % 9;          // ti 0..16, tj 0..8
    int qi0 = ti*4, kj0 = tj*8;
    float acc[4][8];
    #pragma unroll
    for (int i = 0; i < 4; i++)
      #pragma unroll
      for (int j = 0; j < 8; j++) acc[i][j] = 0.f;
    for (int d2 = 0; d2 < 64; d2++) {
      float4 qv = *(const float4*)(qs_t + d2*68 + qi0);
      float4 k0 = *(const float4*)(ks_t + d2*68 + kj0);
      float4 k1 = *(const float4*)(ks_t + d2*68 + kj0 + 4);
      float q_[4] = {qv.x, qv.y, qv.z, qv.w};
      float k_[8] = {k0.x, k0.y, k0.z, k0.w, k1.x, k1.y, k1.z, k1.w};
      #pragma unroll
      for (int i = 0; i < 4; i++)
        #pragma unroll
        for (int j = 0; j < 8; j++)
          acc[i][j] += q_[i]*k_[j];
    }
    #pragma unroll
    for (int i = 0; i < 4; i++) {
      int qi = qi0 + i;
      if (qi >= TT) continue;
      #pragma unroll
      for (int j = 0; j < 8; j++) {
        int kj = kj0 + j;
        if (kj >= TT) continue;
        float s;
        if (qi >= MEM_LEN && kj >= MEM_LEN && kj > qi) s = -1e9f;
        else s = acc[i][j]*0.125f;
        sc[qi*67 + kj] = s;
      }
    }
  }
  __syncthreads();
  if (tid < TT) {
    float* r = sc + tid*67;
    float m = -1e30f;
    for (int j = 0; j < TT; j++) m = fmaxf(m, r[j]);
    float ssum = 0.f;
    for (int j = 0; j < TT; j++) { float e = __expf(r[j]-m); r[j] = e; ssum += e; }
    float inv = 1.f/ssum;
    for (int j = 0; j < TT; j++) r[j] *= inv;
  }
  __syncthreads();
  // ---- PV: O[qi][d2] = sum_kj P[qi][kj] * V[kj][d2] ----
  if (tid < 136) {
    int ti = tid >> 3, tj = tid & 7;         // ti 0..16, tj 0..7
    int qi0 = ti*4, d20 = tj*8;
    float acc[4][8];
    #pragma unroll
    for (int i = 0; i < 4; i++)
      #pragma unroll
      for (int j = 0; j < 8; j++) acc[i][j] = 0.f;
    for (int kj = 0; kj < TT; kj++) {
      float a_[4];
      #pragma unroll
      for (int i = 0; i < 4; i++)
        a_[i] = (qi0 + i < TT) ? sc[(qi0+i)*67 + kj] : 0.f;
      float4 v0 = *(const float4*)(vs + kj*64 + d20);
      float4 v1 = *(const float4*)(vs + kj*64 + d20 + 4);
      float v_[8] = {v0.x, v0.y, v0.z, v0.w, v1.x, v1.y, v1.z, v1.w};
      #pragma unroll
      for (int i = 0; i < 4; i++)
        #pragma unroll
        for (int j = 0; j < 8; j++)
          acc[i][j] += a_[i]*v_[j];
    }
    #pragma unroll
    for (int i = 0; i < 4; i++) {
      int qi = qi0 + i;
      if (qi >= TT) continue;
      _Float16* o = attn_o + ((size_t)b*TT + qi)*D_MODEL + h*DH + d20;
      #pragma unroll
      for (int j = 0; j < 8; j++) o[j] = (_Float16)acc[i][j];
    }
  }
}

// ---------------- finalize+reduce: z + b2 + p0 + p1 -> enc_out / mem / memcand ----------------
__global__ __launch_bounds__(256) void finalize_reduce(
    const float* __restrict__ z, const float* __restrict__ p0, const float* __restrict__ p1,
    const float* __restrict__ b2,
    float* __restrict__ enc_out, float* __restrict__ mem,
    _Float16* __restrict__ mcb, float* __restrict__ mcf, int chunk)
{
  int row = blockIdx.x; int b = row / TT, t = row % TT;
  int d = threadIdx.x * 4;
  size_t idx = (size_t)row*D_MODEL + d;
  float4 v  = *(const float4*)(z  + idx);
  float4 a0 = *(const float4*)(p0 + idx);
  float4 a1 = *(const float4*)(p1 + idx);
  float4 bv = *(const float4*)(b2 + d);
  v.x += a0.x + a1.x + bv.x;
  v.y += a0.y + a1.y + bv.y;
  v.z += a0.z + a1.z + bv.z;
  v.w += a0.w + a1.w + bv.w;
  if (t >= MEM_LEN) {
    size_t o = ((size_t)b*LL + chunk*CHUNK_LEN + (t - MEM_LEN))*D_MODEL + d;
    *(float4*)(enc_out + o) = v;
  } else {
    size_t mrow = (size_t)b*MEM_LEN + t;
    if (chunk == 0) {
      *(float4*)(mem + mrow*D_MODEL + d) = v;
    } else {
      *(float4*)(mcf + mrow*D_MODEL + d) = v;
      _Float16* o = mcb + mrow*D_MODEL + d;
      o[0] = (_Float16)v.x;
      o[1] = (_Float16)v.y;
      o[2] = (_Float16)v.z;
      o[3] = (_Float16)v.w;
    }
  }
}

// ---------------- copy mem -> output tail ----------------
__global__ __launch_bounds__(256) void copy_mem_kernel(const float* __restrict__ mem,
                                                       float* __restrict__ out) {
  int i = (blockIdx.x * 256 + threadIdx.x) * 4;
  float4 v = *(const float4*)(mem + i);
  *(float4*)(out + i) = v;
}

// ---------------- GEMM: C = A(MxK_total) @ Bw(NxK_total)^T, fp16 in / f32 acc ----------------
// K-loop: double-buffered, counted s_waitcnt vmcnt(4) (next tile's loads stay in
// flight across raw s_barrier), LDS XOR-swizzle (both sides: pre-swizzled global
// source for gload_lds + swizzled ds_read) kills the 8-way bank conflict.
#define EPI_QKV   0
#define EPI_RESID 1
#define EPI_RELU  2
#define EPI_PART  3   // split-K partial: write raw acc (no bias) to p0/p1 per blockIdx.z

#define KSLICE 2048

template<int EPI>
__global__ __launch_bounds__(256) void gemm_bt(
    const _Float16* __restrict__ A,
    const _Float16* __restrict__ Bw,
    const float* __restrict__ bias,
    float* __restrict__ zres,      // EPI_RESID: residual; EPI_PART: partial 0
    _Float16* __restrict__ obf,
    float* __restrict__ p1,        // EPI_PART: partial 1
    int K, int lda, int ldo)
{
  __shared__ short As[2][128*32];
  __shared__ short Bs[2][128*32];
  int tid = threadIdx.x;
  int lane = tid & 63, wave = tid >> 6;
  int wr = wave >> 1, wc = wave & 1;
  int tm = blockIdx.y * 128, tn = blockIdx.x * 128;
  f32x4 acc[4][4] = {};
  const short* Ash = (const short*)A;
  const short* Bsh = (const short*)Bw;
  if constexpr (EPI == EPI_PART) {
    Ash += (size_t)blockIdx.z * KSLICE;
    Bsh += (size_t)blockIdx.z * KSLICE;
  }
  int e0 = tid * 8;
  int r0 = e0 >> 5, c0 = e0 & 31;
  // pre-swizzled global source column (shorts): involution XOR with ((row>>1)&3)<<3
  int c0s = c0 ^ (((r0 >> 1) & 3) << 3);
  int ko = (lane >> 4) * 8;
  int rr = lane & 15;
  int swz = ((rr >> 1) & 3) << 3;     // read-side XOR (shorts), row base mult of 16 -> rr only

  auto STAGE = [&](int buf, int kt) {
    gload16(Ash + (size_t)(tm +      r0)*lda + kt + c0s, (char*)&As[buf][0] +        wave*1024);
    gload16(Ash + (size_t)(tm + 64 + r0)*lda + kt + c0s, (char*)&As[buf][0] + 4096 + wave*1024);
    gload16(Bsh + (size_t)(tn +      r0)*lda + kt + c0s, (char*)&Bs[buf][0] +        wave*1024);
    gload16(Bsh + (size_t)(tn + 64 + r0)*lda + kt + c0s, (char*)&Bs[buf][0] + 4096 + wave*1024);
  };
  auto COMPUTE = [&](int buf) {
    half8_t af[4], bfr[4];
    int kos = ko ^ swz;
    #pragma unroll
    for (int m = 0; m < 4; m++)
      af[m] = *(const half8_t*)(&As[buf][(wr*64 + m*16 + rr)*32 + kos]);
    #pragma unroll
    for (int n = 0; n < 4; n++)
      bfr[n] = *(const half8_t*)(&Bs[buf][(wc*64 + n*16 + rr)*32 + kos]);
    #pragma unroll
    for (int m = 0; m < 4; m++)
      #pragma unroll
      for (int n = 0; n < 4; n++)
        acc[m][n] = __builtin_amdgcn_mfma_f32_16x16x32_f16(af[m], bfr[n], acc[m][n], 0, 0, 0);
  };

  STAGE(0, 0);
  int cur = 0;
  for (int kt = 32; kt < K; kt += 32) {
    STAGE(cur ^ 1, kt);
    // wait for CURRENT buffer's 4 loads only; next tile's 4 stay in flight
    asm volatile("s_waitcnt vmcnt(4)" ::: "memory");
    __builtin_amdgcn_s_barrier();
    COMPUTE(cur);
    asm volatile("" ::: "memory");
    __builtin_amdgcn_s_barrier();
    cur ^= 1;
  }
  asm volatile("s_waitcnt vmcnt(0)" ::: "memory");
  __builtin_amdgcn_s_barrier();
  COMPUTE(cur);

  int rbase = tm + wr*64 + ((lane >> 4) << 2);
  int cbase = tn + wc*64 + (lane & 15);
  float* pp = nullptr;
  if constexpr (EPI == EPI_PART) pp = (blockIdx.z == 0) ? zres : p1;
  #pragma unroll
  for (int n = 0; n < 4; n++) {
    int col = cbase + n*16;
    float bs = (EPI == EPI_PART) ? 0.f : bias[col];
    #pragma unroll
    for (int m = 0; m < 4; m++) {
      #pragma unroll
      for (int i = 0; i < 4; i++) {
        int r = rbase + m*16 + i;
        float v = acc[m][n][i] + bs;
        if constexpr (EPI == EPI_QKV) {
          obf[(size_t)r*ldo + col] = (_Float16)v;
        } else if constexpr (EPI == EPI_RESID) {
          zres[(size_t)r*D_MODEL + col] += v;
        } else if constexpr (EPI == EPI_RELU) {
          obf[(size_t)r*ldo + col] = (_Float16)fmaxf(v, 0.f);
        } else { // EPI_PART
          pp[(size_t)r*D_MODEL + col] = v;
        }
      }
    }
  }
}

// ---------------- gate GEMM: 64x64 tiles, M=N=K=1024, sigmoid + mem blend ----------------
__global__ __launch_bounds__(256) void gemm_gate64(
    const _Float16* __restrict__ A,    // mem candidate fp16 [1024][1024]
    const _Float16* __restrict__ Bw,   // w_gate fp16 [1024][1024]
    const float* __restrict__ bias,
    const float* __restrict__ mcf,     // mem candidate fp32
    float* __restrict__ mem)           // in/out
{
  __shared__ short As[64*32];
  __shared__ short Bs[64*32];
  int tid = threadIdx.x;
  int lane = tid & 63, wave = tid >> 6;
  int wr = wave >> 1, wc = wave & 1;
  int tm = blockIdx.y * 64, tn = blockIdx.x * 64;
  f32x4 acc[2][2] = {};
  const short* Ash = (const short*)A;
  const short* Bsh = (const short*)Bw;
  int e0 = tid * 8;
  int r0 = e0 >> 5, c0 = e0 & 31;

  for (int kt = 0; kt < 1024; kt += 32) {
    gload16(Ash + (size_t)(tm + r0)*1024 + kt + c0, (char*)As + wave*1024);
    gload16(Bsh + (size_t)(tn + r0)*1024 + kt + c0, (char*)Bs + wave*1024);
    __syncthreads();
    half8_t af[2], bfr[2];
    int ko = (lane >> 4) * 8;
    int rr = lane & 15;
    #pragma unroll
    for (int m = 0; m < 2; m++)
      af[m] = *(const half8_t*)(As + (wr*32 + m*16 + rr)*32 + ko);
    #pragma unroll
    for (int n = 0; n < 2; n++)
      bfr[n] = *(const half8_t*)(Bs + (wc*32 + n*16 + rr)*32 + ko);
    #pragma unroll
    for (int m = 0; m < 2; m++)
      #pragma unroll
      for (int n = 0; n < 2; n++)
        acc[m][n] = __builtin_amdgcn_mfma_f32_16x16x32_f16(af[m], bfr[n], acc[m][n], 0, 0, 0);
    __syncthreads();
  }

  int rbase = tm + wr*32 + ((lane >> 4) << 2);
  int cbase = tn + wc*32 + (lane & 15);
  #pragma unroll
  for (int n = 0; n < 2; n++) {
    int col = cbase + n*16;
    float bs = bias[col];
    #pragma unroll
    for (int m = 0; m < 2; m++) {
      #pragma unroll
      for (int i = 0; i < 4; i++) {
        int r = rbase + m*16 + i;
        float g = 1.f / (1.f + __expf(-(acc[m][n][i] + bs)));
        size_t mi = (size_t)r*D_MODEL + col;
        mem[mi] = g*mcf[mi] + (1.f - g)*mem[mi];
      }
    }
  }
}

extern "C" void kernel_launch(void* const* d_in, const int* in_sizes, int n_in,
                              void* d_out, int out_size, void* d_ws, size_t ws_size,
                              hipStream_t stream) {
  const int*   in_prob  = (const int*)d_in[0];
  const int*   in_skill = (const int*)d_in[1];
  const float* emb_p    = (const float*)d_in[2];
  const float* emb_s    = (const float*)d_in[3];
  const float* mem_init = (const float*)d_in[4];
  const float* pos      = (const float*)d_in[5];
  const float* w_qkv    = (const float*)d_in[6];
  const float* b_qkv    = (const float*)d_in[7];
  const float* w_out    = (const float*)d_in[8];
  const float* b_out    = (const float*)d_in[9];
  const float* w1       = (const float*)d_in[10];
  const float* b1       = (const float*)d_in[11];
  const float* w2       = (const float*)d_in[12];
  const float* b2       = (const float*)d_in[13];
  const float* g_attn   = (const float*)d_in[14];
  const float* be_attn  = (const float*)d_in[15];
  const float* g_ffn    = (const float*)d_in[16];
  const float* be_ffn   = (const float*)d_in[17];
  const float* w_gate   = (const float*)d_in[18];
  const float* b_gate   = (const float*)d_in[19];

  float* enc_out = (float*)d_out;
  float* mem_out = enc_out + (size_t)BB*LL*D_MODEL;

  char* ws = (char*)d_ws;
  size_t off = 0;
  auto alloc = [&](size_t bytes) -> char* {
    char* p = ws + off;
    off += (bytes + 255) & ~(size_t)255;
    return p;
  };
  _Float16* wqkv_h = (_Float16*)alloc((size_t)3072*1024*2);
  _Float16* wout_h = (_Float16*)alloc((size_t)1024*1024*2);
  _Float16* w1_h   = (_Float16*)alloc((size_t)4096*1024*2);
  _Float16* w2_h   = (_Float16*)alloc((size_t)1024*4096*2);
  _Float16* wgate_h= (_Float16*)alloc((size_t)1024*1024*2);
  float*    z      = (float*)alloc((size_t)MTOK*D_MODEL*4);
  _Float16* zn     = (_Float16*)alloc((size_t)MTOK*D_MODEL*2);
  _Float16* qkv    = (_Float16*)alloc((size_t)MTOK*3072*2);
  _Float16* ao     = (_Float16*)alloc((size_t)MTOK*D_MODEL*2);
  _Float16* hb     = (_Float16*)alloc((size_t)MTOK*D_MODEL*2);
  _Float16* fh     = (_Float16*)alloc((size_t)MTOK*4096*2);
  _Float16* mcb    = (_Float16*)alloc((size_t)1024*1024*2);
  float*    mem    = (float*)alloc((size_t)1024*1024*4);
  float*    mcf    = (float*)alloc((size_t)1024*1024*4);
  float*    part0  = (float*)alloc((size_t)MTOK*D_MODEL*4);
  float*    part1  = (float*)alloc((size_t)MTOK*D_MODEL*4);
  if (off > ws_size) return;  // workspace too small -> fail loudly via wrong output

  // weights -> fp16 (cheap, once per call)
  f2h_kernel<<<(3072*1024)/1024, 256, 0, stream>>>(w_qkv, wqkv_h, 3072*1024);
  f2h_kernel<<<(1024*1024)/1024, 256, 0, stream>>>(w_out, wout_h, 1024*1024);
  f2h_kernel<<<(4096*1024)/1024, 256, 0, stream>>>(w1, w1_h, 4096*1024);
  f2h_kernel<<<(1024*4096)/1024, 256, 0, stream>>>(w2, w2_h, 1024*4096);
  f2h_kernel<<<(1024*1024)/1024, 256, 0, stream>>>(w_gate, wgate_h, 1024*1024);

  for (int c = 0; c < NCHUNK; c++) {
    const float* msrc = (c == 0) ? mem_init : mem;
    int mbs = (c == 0) ? 0 : MEM_LEN*D_MODEL;
    build_z_ln<<<MTOK, 256, 0, stream>>>(in_prob, in_skill, emb_p, emb_s,
                                         msrc, mbs, pos, g_attn, be_attn, z, zn, c);
    gemm_bt<EPI_QKV><<<dim3(3072/128, MTOK/128), 256, 0, stream>>>(
        zn, wqkv_h, b_qkv, nullptr, qkv, nullptr, 1024, 1024, 3072);
    attn_kernel<<<BB*N_HEADS, 256, 0, stream>>>(qkv, ao);
    gemm_bt<EPI_RESID><<<dim3(1024/128, MTOK/128), 256, 0, stream>>>(
        ao, wout_h, b_out, z, nullptr, nullptr, 1024, 1024, 1024);
    ln_kernel<<<MTOK, 256, 0, stream>>>(z, g_ffn, be_ffn, hb);
    gemm_bt<EPI_RELU><<<dim3(4096/128, MTOK/128), 256, 0, stream>>>(
        hb, w1_h, b1, nullptr, fh, nullptr, 1024, 1024, 4096);
    // FFN2 split-K=2: each z-slice covers K=2048 of 4096
    gemm_bt<EPI_PART><<<dim3(1024/128, MTOK/128, 2), 256, 0, stream>>>(
        fh, w2_h, b2, part0, nullptr, part1, KSLICE, 4096, 1024);
    finalize_reduce<<<MTOK, 256, 0, stream>>>(z, part0, part1, b2,
                                              enc_out, mem, mcb, mcf, c);
    if (c > 0) {
      gemm_gate64<<<dim3(1024/64, 1024/64), 256, 0, stream>>>(
          mcb, wgate_h, b_gate, mcf, mem);
    }
  }
  copy_mem_kernel<<<(1024*1024)/1024, 256, 0, stream>>>(mem, mem_out);
}